// Round 1
// baseline (197.354 us; speedup 1.0000x reference)
//
#include <hip/hip_runtime.h>
#include <math.h>

#define IMG_H 256
#define IMG_W 256
#define NANG  180
#define NDET  363
#define NBAT  4

// One block per (angle, batch). 256 threads = one per image column j.
// Each thread sums bilinear samples over i (the meshgrid row index),
// then the block does the detector resample out of LDS.
__global__ __launch_bounds__(256) void radon_kernel(const float* __restrict__ x,
                                                    float* __restrict__ out) {
    const int blk = blockIdx.x;
    const int a = blk >> 2;       // angle index
    const int b = blk & 3;        // batch index
    const int j = threadIdx.x;

    const float* __restrict__ img = x + (size_t)b * (IMG_H * IMG_W);

    // angles = a * pi/180 ; cos_t = cos(-ang), sin_t = sin(-ang)
    const float ang = (float)a * 0.017453292519943295f;
    const float cs = cosf(ang);
    const float sn = -sinf(ang);

    // xc[j] = -1 + 2j/255
    const float xcj = -1.0f + (2.0f / 255.0f) * (float)j;
    const float gx0 = xcj * cs;   // gx = gx0 - yci*sn
    const float gy0 = xcj * sn;   // gy = gy0 + yci*cs

    float sum = 0.0f;

    #pragma unroll 4
    for (int i = 0; i < IMG_H; ++i) {
        const float yci = -1.0f + (2.0f / 255.0f) * (float)i;
        const float gx = gx0 - yci * sn;
        const float gy = gy0 + yci * cs;
        const float fx = (gx + 1.0f) * 127.5f;
        const float fy = (gy + 1.0f) * 127.5f;

        const float flx = floorf(fx);
        const float fly = floorf(fy);
        const int x0 = (int)flx;
        const int y0 = (int)fly;
        const float wx = fx - flx;
        const float wy = fy - fly;

        const bool vx0 = ((unsigned)x0 < IMG_W);
        const bool vx1 = ((unsigned)(x0 + 1) < IMG_W);
        const bool vy0 = ((unsigned)y0 < IMG_H);
        const bool vy1 = ((unsigned)(y0 + 1) < IMG_H);

        if (!((vx0 | vx1) & (vy0 | vy1))) continue;  // all 4 taps outside

        const int xc0 = min(max(x0, 0), IMG_W - 1);
        const int xc1 = min(max(x0 + 1, 0), IMG_W - 1);
        const int yc0 = min(max(y0, 0), IMG_H - 1);
        const int yc1 = min(max(y0 + 1, 0), IMG_H - 1);

        const float* r0 = img + yc0 * IMG_W;
        const float* r1 = img + yc1 * IMG_W;

        const float v00 = (vy0 && vx0) ? r0[xc0] : 0.0f;
        const float v01 = (vy0 && vx1) ? r0[xc1] : 0.0f;
        const float v10 = (vy1 && vx0) ? r1[xc0] : 0.0f;
        const float v11 = (vy1 && vx1) ? r1[xc1] : 0.0f;

        sum += (1.0f - wy) * ((1.0f - wx) * v00 + wx * v01)
             +         wy  * ((1.0f - wx) * v10 + wx * v11);
    }

    __shared__ float proj[IMG_W];
    proj[j] = sum;
    __syncthreads();

    // detector resample: pos = d * 255/362, linear interp of proj
    for (int d = j; d < NDET; d += 256) {
        const float pos = (float)d * (255.0f / 362.0f);
        const float fp = floorf(pos);
        const int p0 = (int)fp;
        const int p1 = min(p0 + 1, IMG_W - 1);
        const float w = pos - fp;
        const float val = proj[p0] * (1.0f - w) + proj[p1] * w;
        out[(size_t)b * (NANG * NDET) + a * NDET + d] = val;
    }
}

extern "C" void kernel_launch(void* const* d_in, const int* in_sizes, int n_in,
                              void* d_out, int out_size, void* d_ws, size_t ws_size,
                              hipStream_t stream) {
    const float* x = (const float*)d_in[0];
    float* out = (float*)d_out;
    (void)in_sizes; (void)n_in; (void)out_size; (void)d_ws; (void)ws_size;
    radon_kernel<<<dim3(NANG * NBAT), dim3(256), 0, stream>>>(x, out);
}